// Round 11
// baseline (319.944 us; speedup 1.0000x reference)
//
#include <hip/hip_runtime.h>

#define DD 384
#define NB 64
#define NATOM 8192
#define NTX 24              // 16px tiles per axis
#define NTILE (NTX * NTX)   // 576 tiles per image
#define LSTRIDE 51200       // list entries per image >= 4*8192 + 576*31 = 50624

typedef short short8 __attribute__((ext_vector_type(8)));
typedef float f32x4 __attribute__((ext_vector_type(4)));
typedef unsigned u32x4 __attribute__((ext_vector_type(4)));

// float -> bf16 (RNE) as ushort
__device__ inline unsigned bf1(float a) {
    unsigned u = __float_as_uint(a);
    return (u + 0x7FFFu + ((u >> 16) & 1u)) >> 16;
}
__device__ inline unsigned bfpack(float a, float b) {
    return bf1(a) | (bf1(b) << 16);
}

// Pose one atom -> (X, Y) in physical coords.
__device__ inline float2 pose_one(const float* __restrict__ crd,
                                  const float* __restrict__ rot,
                                  const float* __restrict__ rot_init,
                                  const float* __restrict__ trans, int idx) {
    int b = idx >> 13;
    const float* p = crd + (long)idx * 3;
    float x0 = p[0], y0 = p[1], z0 = p[2];
    float q0 = x0 * rot_init[0] + y0 * rot_init[3] + z0 * rot_init[6] + trans[0];
    float q1 = x0 * rot_init[1] + y0 * rot_init[4] + z0 * rot_init[7] + trans[1];
    float q2 = x0 * rot_init[2] + y0 * rot_init[5] + z0 * rot_init[8] + trans[2];
    const float* R = rot + b * 9;
    float2 o;
    o.x = q0 * R[0] + q1 * R[1] + q2 * R[2];
    o.y = q0 * R[3] + q1 * R[4] + q2 * R[5];
    return o;
}

// ---------------------------------------------------------------------------
// R11 bucketing: per-TILE contiguous lists with replication. Each atom's +-5
// window touches <=2x2 16px tiles (avg 2.64); count/scatter add it to each.
// Lists are 32-padded (scan rounds allocation; pad slots hold the 0x45-memset
// sentinel ~3.2e3 -> all masks false -> exact zero contribution). This gives
// the splat ONE contiguous exact-window segment per tile: no LDS staging, no
// offset walking, no prefix-scan copy loop (R10 splat spent ~10x its compute
// in that orchestration).
// ---------------------------------------------------------------------------
__global__ void count_atoms(const float* __restrict__ crd,
                            const float* __restrict__ rot,
                            const float* __restrict__ rot_init,
                            const float* __restrict__ trans,
                            int* __restrict__ counts,
                            float2* __restrict__ posed) {
    int idx = blockIdx.x * 256 + threadIdx.x;
    float2 v = pose_one(crd, rot, rot_init, trans, idx);
    posed[idx] = v;
    int icx = (int)rintf(v.x + 192.0f);
    int icy = (int)rintf(v.y + 192.0f);
    int x0 = max(icx - 5, 0), x1 = min(icx + 5, DD - 1);
    int y0 = max(icy - 5, 0), y1 = min(icy + 5, DD - 1);
    if (x0 > x1 || y0 > y1) return;          // window misses the image
    int tx0 = x0 >> 4, tx1 = x1 >> 4, ty0 = y0 >> 4, ty1 = y1 >> 4;
    int* cb = counts + (idx >> 13) * NTILE;
    for (int ty = ty0; ty <= ty1; ++ty)
        for (int tx = tx0; tx <= tx1; ++tx)
            atomicAdd(&cb[ty * NTX + tx], 1);
}

// Per-image exclusive scan of 576 rounded-to-32 tile counts (single pass).
__global__ __launch_bounds__(1024) void tile_scan(int* __restrict__ counts,
                                                  int* __restrict__ offs) {
    int b = blockIdx.x, t = threadIdx.x;
    int lane = t & 63, wid = t >> 6;     // 16 waves
    int* cnt = counts + b * NTILE;
    int* off = offs + b * NTILE;
    __shared__ int wsum[16];
    int v = (t < NTILE) ? cnt[t] : 0;
    int r = (v + 31) & ~31;              // padded allocation
    int incl = r;
#pragma unroll
    for (int d = 1; d < 64; d <<= 1) {
        int u = __shfl_up(incl, d);
        if (lane >= d) incl += u;
    }
    if (lane == 63) wsum[wid] = incl;
    __syncthreads();
    if (wid == 0) {
        int s = (lane < 16) ? wsum[lane] : 0;
        int si = s;
#pragma unroll
        for (int d = 1; d < 16; d <<= 1) {
            int u = __shfl_up(si, d);
            if (lane >= d) si += u;
        }
        if (lane < 16) wsum[lane] = si - s;  // exclusive
    }
    __syncthreads();
    if (t < NTILE) {
        off[t] = incl - r + wsum[wid];
        cnt[t] = 0;                      // reuse as scatter cursor
    }
}

__global__ void scatter_atoms(const float2* __restrict__ posed,
                              int* __restrict__ cursors,
                              const int* __restrict__ offs,
                              float2* __restrict__ lists) {
    int idx = blockIdx.x * 256 + threadIdx.x;
    float2 v = posed[idx];               // coalesced 8B re-read (same bits)
    int icx = (int)rintf(v.x + 192.0f);
    int icy = (int)rintf(v.y + 192.0f);
    int x0 = max(icx - 5, 0), x1 = min(icx + 5, DD - 1);
    int y0 = max(icy - 5, 0), y1 = min(icy + 5, DD - 1);
    if (x0 > x1 || y0 > y1) return;
    int b = idx >> 13;
    int* cb = cursors + b * NTILE;
    const int* ob = offs + b * NTILE;
    float2* lb = lists + (long)b * LSTRIDE;
    int tx0 = x0 >> 4, tx1 = x1 >> 4, ty0 = y0 >> 4, ty1 = y1 >> 4;
    for (int ty = ty0; ty <= ty1; ++ty)
        for (int tx = tx0; tx <= tx1; ++tx) {
            int tt = ty * NTX + tx;
            int pos = atomicAdd(&cb[tt], 1);
            lb[ob[tt] + pos] = v;
        }
}

// ---------------------------------------------------------------------------
// MFMA splat, tile-direct (see R6/R11 notes). Gaussian separability: per
// 16x16 tile IMG = sum_a ey_a (x) ex_a = E_y^T*E_x, a GEMM with K = atoms;
// 32 atoms per mfma_f32_16x16x32_bf16. Lanes read their k-slice DIRECTLY
// from the tile's contiguous global segment (16-lane broadcast f32x4 loads);
// tail chunk reads pre-memset sentinel atoms (masked to exact 0).
// Epilogue writes f32 Y and a bf16 (RNE) copy for stage-1's B operand.
// ---------------------------------------------------------------------------
__global__ __launch_bounds__(256) void splat_mfma(const float2* __restrict__ lists,
                                                  const int* __restrict__ offs,
                                                  const int* __restrict__ cnts,
                                                  float* __restrict__ img,
                                                  unsigned short* __restrict__ img_bf) {
    int b = blockIdx.z;
    int wv = __builtin_amdgcn_readfirstlane((int)(threadIdx.x >> 6));
    int lane = threadIdx.x & 63;
    int tx = blockIdx.x * 4 + wv;      // 0..23
    int ty = blockIdx.y;               // 0..23
    int c0 = tx * 16, r0 = ty * 16;
    int tt = ty * NTX + tx;

    int i0 = offs[b * NTILE + tt];
    int n  = cnts[b * NTILE + tt];     // cursors == tile count after scatter
    const float2* lb = lists + (long)b * LSTRIDE + i0;

    f32x4 acc = {0.f, 0.f, 0.f, 0.f};
    int m = lane & 15;
    float rowf = (float)(r0 + m);        // a-side: pixel row (0..383)
    float colf = (float)(c0 + m);        // b-side: pixel col
    float py = rowf - 192.0f, px = colf - 192.0f;
    int g8 = (lane >> 4) << 3;           // k-slice base within chunk
    const float kneg = -0.32059868f;     // -(1/4.5)*log2(e)

    int nch = (n + 31) >> 5;
    for (int ch = 0; ch < nch; ch++) {
        const f32x4* qp = (const f32x4*)(lb + ch * 32 + g8);  // 2 atoms/read
        u32x4 au, bu;
#pragma unroll
        for (int p = 0; p < 4; p++) {
            f32x4 q = qp[p];         // (X0,Y0,X1,Y1); 16-lane broadcast
            // ey (row side)
            float d0 = py - q[1], d1 = py - q[3];
            float cy0 = rintf(q[1] + 192.0f), cy1 = rintf(q[3] + 192.0f);
            float e0 = (fabsf(rowf - cy0) <= 5.0f) ? exp2f(d0 * d0 * kneg) : 0.0f;
            float e1 = (fabsf(rowf - cy1) <= 5.0f) ? exp2f(d1 * d1 * kneg) : 0.0f;
            au[p] = bfpack(e0, e1);
            // ex (col side)
            float f0 = px - q[0], f1 = px - q[2];
            float cx0 = rintf(q[0] + 192.0f), cx1 = rintf(q[2] + 192.0f);
            float g0 = (fabsf(colf - cx0) <= 5.0f) ? exp2f(f0 * f0 * kneg) : 0.0f;
            float g1 = (fabsf(colf - cx1) <= 5.0f) ? exp2f(f1 * f1 * kneg) : 0.0f;
            bu[p] = bfpack(g0, g1);
        }
        short8 af = __builtin_bit_cast(short8, au);
        short8 bf = __builtin_bit_cast(short8, bu);
        acc = __builtin_amdgcn_mfma_f32_16x16x32_bf16(af, bf, acc, 0, 0, 0);
    }

    // C layout: col = lane&15, row = (lane>>4)*4 + r  (same as gemm_mfma)
    int col = c0 + m;
    int rbase = r0 + (lane >> 4) * 4;
#pragma unroll
    for (int r = 0; r < 4; r++) {
        long o = ((long)b * DD + rbase + r) * DD + col;
        img[o] = acc[r];
        img_bf[o] = (unsigned short)bf1(acc[r]);
    }
}

// ---------------------------------------------------------------------------
// DFT-derived weights (bf16): Bt1 = [U; S] (768x384), Bt2 = [U|-2S] (384x768).
// y = U*Y*U - 2*S*Y*S == Re(f)-Im(f) of double-fftshifted FFT2.
// ---------------------------------------------------------------------------
__global__ void gen_w(unsigned short* __restrict__ Bt1,
                      unsigned short* __restrict__ Bt2) {
    int idx = blockIdx.x * 256 + threadIdx.x;
    if (idx >= DD * DD) return;
    int i = idx / DD, j = idx % DD;
    int t = (i - 192) * (j - 192);
    int r = t % DD;
    if (r < 0) r += DD;
    float th = (float)r * (6.28318530717958647692f / (float)DD);
    float s = sinf(th), c = cosf(th);
    Bt1[i * DD + j] = (unsigned short)bf1(c + s);
    Bt1[(DD + i) * DD + j] = (unsigned short)bf1(s);
    Bt2[i * 768 + j] = (unsigned short)bf1(c + s);
    Bt2[i * 768 + 384 + j] = (unsigned short)bf1(-2.0f * s);
}

// ---------------------------------------------------------------------------
// bf16 MFMA GEMM: C[row][col] = sum_k A[row][k] * B[col][k].
// A is the SHARED bf16 weight matrix (row stride K). B is BATCHED (stride sB).
// 1D grid + bijective XCD swizzle (R7: FETCH 117->27MB) + T2 LDS XOR swizzle
// (R9: bank-conflict 1.24e7 -> fixed, -40us). BFOLD: B is the folded view of
// stage-1's C' (768x384 bf16): B[i][k] = k<384 ? C'[i][k] : C'[384+i][k-384].
// ---------------------------------------------------------------------------
template <bool CBF16, bool BFOLD>
__global__ __launch_bounds__(256) void gemm_mfma(const unsigned short* __restrict__ Ag,
                                                 const unsigned short* __restrict__ Bg,
                                                 long sB,
                                                 void* __restrict__ Cg, long sC,
                                                 int K, int ldc, int nx, int bpi) {
    __shared__ uint4 lds4[2048];  // A: [0,1024), B: [1024,2048)

    int cpx = gridDim.x >> 3;                 // blocks per XCD chunk
    int wg = blockIdx.x;
    int lin = (wg & 7) * cpx + (wg >> 3);     // bijective XCD swizzle
    int bz = lin / bpi;
    int rr = lin - bz * bpi;
    int m0 = (rr / nx) * 128, n0 = (rr % nx) * 128;
    int tid = threadIdx.x;
    int lane = tid & 63, w = tid >> 6;
    int wm = w >> 1, wn = w & 1;

    f32x4 acc[4][4];
#pragma unroll
    for (int i = 0; i < 4; i++)
#pragma unroll
        for (int j = 0; j < 4; j++) acc[i][j] = (f32x4){0.f, 0.f, 0.f, 0.f};

    const unsigned short* Bh = Bg + (long)bz * sB;

    // read-side swizzled lane offset (same function of the logical index)
    int lsw = lane ^ (((lane >> 4) & 3) << 1);

    for (int k0 = 0; k0 < K; k0 += 64) {
        __syncthreads();
#pragma unroll
        for (int cc = 0; cc < 4; cc++) {
            int c = tid + cc * 256;
            int m = c >> 3, kc = (c & 7) << 3;
            int li = ((m >> 4) * 2 + (kc >> 5)) * 64 +
                     ((m & 15) | (((kc >> 3) & 3) << 4));
            li ^= ((kc >> 3) & 3) << 1;   // T2 swizzle (== ((li>>4)&3)<<1)
            // A tile (shared weights, always bf16, row stride K)
            lds4[li] = *(const uint4*)(Ag + (long)(m0 + m) * K + k0 + kc);
            // B tile (batched bf16)
            uint4 wv;
            if (BFOLD) {
                int kk = k0 + kc;  // 16B run stays within one 384-half (64|384)
                long boff = (kk >= 384)
                                ? ((long)(384 + n0 + m) * 384 + (kk - 384))
                                : ((long)(n0 + m) * 384 + kk);
                wv = *(const uint4*)(Bh + boff);
            } else {
                wv = *(const uint4*)(Bh + (long)(n0 + m) * K + k0 + kc);
            }
            lds4[1024 + li] = wv;
        }
        __syncthreads();
#pragma unroll
        for (int ki = 0; ki < 2; ki++) {
            short8 a[4], bfr[4];
#pragma unroll
            for (int i = 0; i < 4; i++)
                a[i] = *(const short8*)&lds4[((wm * 4 + i) * 2 + ki) * 64 + lsw];
#pragma unroll
            for (int j = 0; j < 4; j++)
                bfr[j] = *(const short8*)&lds4[1024 + ((wn * 4 + j) * 2 + ki) * 64 + lsw];
#pragma unroll
            for (int i = 0; i < 4; i++)
#pragma unroll
                for (int j = 0; j < 4; j++)
                    acc[i][j] = __builtin_amdgcn_mfma_f32_16x16x32_bf16(
                        a[i], bfr[j], acc[i][j], 0, 0, 0);
        }
    }

    int quad = lane >> 4, col0 = lane & 15;
#pragma unroll
    for (int i = 0; i < 4; i++)
#pragma unroll
        for (int j = 0; j < 4; j++)
#pragma unroll
            for (int r = 0; r < 4; r++) {
                int row = m0 + (wm * 4 + i) * 16 + quad * 4 + r;
                int cc2 = n0 + (wn * 4 + j) * 16 + col0;
                if (CBF16)
                    ((unsigned short*)Cg + (long)bz * sC)[(long)row * ldc + cc2] =
                        (unsigned short)bf1(acc[i][j][r]);
                else
                    ((float*)Cg + (long)bz * sC)[(long)row * ldc + cc2] = acc[i][j][r];
            }
}

extern "C" void kernel_launch(void* const* d_in, const int* in_sizes, int n_in,
                              void* d_out, int out_size, void* d_ws, size_t ws_size,
                              hipStream_t stream) {
    const float* crd      = (const float*)d_in[0];
    const float* rot      = (const float*)d_in[1];
    const float* rot_init = (const float*)d_in[2];
    const float* trans    = (const float*)d_in[3];

    float* out   = (float*)d_out;
    float* y     = out;                          // [64,384,384] hartley (fp32)
    float* yreal = out + (size_t)NB * DD * DD;   // [64,384,384] real image
    // Ybf16 staging lives in the y output region (18.9MB < 37.7MB): written
    // by splat, read by stage-1, overwritten by stage-2's final y write.
    unsigned short* Ybf = (unsigned short*)y;

    char* ws = (char*)d_ws;
    unsigned short* Bt1 = (unsigned short*)ws;              // [U;S]   768x384
    unsigned short* Bt2 = (unsigned short*)(ws + 589824);   // [U|-2S] 384x768
    char* Zb = ws + 1179648;                                // Z region (37.7MB)
    unsigned short* Z = (unsigned short*)Zb;                // 64x768x384 bf16 (Z^T)
    // Bucketing scratch aliases Z (all dead before stage-1 GEMM writes Z):
    int*    counts = (int*)Zb;                              // 576*64*4 = 147,456 B
    int*    offs   = (int*)(Zb + 147456);                   // 147,456 B
    float2* posed  = (float2*)(Zb + 294912);                // 4,194,304 B
    float2* lists  = (float2*)(Zb + 4489216);               // 64*51200*8 = 26,214,400 B
    // ends at 30,703,616 < 37,748,736 (Z size)

    hipMemsetAsync(counts, 0, (size_t)NB * NTILE * 4, stream);
    // Sentinel-fill the lists: 0x45454545 as float ~= 3.2e3 -> icx/icy far
    // outside any tile => every mask false => pad atoms contribute exact 0.
    hipMemsetAsync(lists, 0x45, (size_t)NB * LSTRIDE * 8, stream);

    count_atoms<<<(NB * NATOM) / 256, 256, 0, stream>>>(crd, rot, rot_init, trans,
                                                        counts, posed);
    tile_scan<<<NB, 1024, 0, stream>>>(counts, offs);
    scatter_atoms<<<(NB * NATOM) / 256, 256, 0, stream>>>(posed, counts, offs, lists);
    splat_mfma<<<dim3(6, 24, NB), 256, 0, stream>>>(lists, offs, counts, yreal, Ybf);

    gen_w<<<(DD * DD + 255) / 256, 256, 0, stream>>>(Bt1, Bt2);

    // Stage 1 (swapped): C'[v][k] = sum_m Bt1[v][m]*Y[k][m] = Z^T,
    // M=768, N=384, K=384; A=Bt1 shared, B=Ybf batched bf16, C bf16.
    // nx=3 (384/128), bpi=3*6=18, nwg=18*64=1152 (div by 8 -> swizzle ok).
    gemm_mfma<true, false><<<1152, 256, 0, stream>>>(
        Bt1, Ybf, (long)DD * DD, (void*)Z, (long)768 * DD, DD, DD, 3, 18);

    // Stage 2 (swapped, folded-B): y[j][i] = sum_k Bt2[j][k]*Zt[i][k],
    // M=N=384, K=768; A=Bt2 shared, B=C' via fold addressing, C=y f32 direct.
    // nx=3, bpi=3*3=9, nwg=9*64=576 (div by 8 -> swizzle ok).
    gemm_mfma<false, true><<<576, 256, 0, stream>>>(
        Bt2, Z, (long)768 * DD, (void*)y, (long)DD * DD, 768, DD, 3, 9);
}

// Round 12
// 307.917 us; speedup vs baseline: 1.0391x; 1.0391x over previous
//
#include <hip/hip_runtime.h>

#define DD 384
#define NB 64
#define NATOM 8192
#define NTX 24              // 16px tiles per axis
#define NTILE (NTX * NTX)   // 576 tiles per image
#define OFFST (NTILE + 1)
#define LSTRIDE (NATOM + 32)  // per-image list entries + sentinel pad

typedef short short8 __attribute__((ext_vector_type(8)));
typedef float f32x4 __attribute__((ext_vector_type(4)));
typedef unsigned u32x4 __attribute__((ext_vector_type(4)));

// float -> bf16 (RNE) as ushort
__device__ inline unsigned bf1(float a) {
    unsigned u = __float_as_uint(a);
    return (u + 0x7FFFu + ((u >> 16) & 1u)) >> 16;
}
__device__ inline unsigned bfpack(float a, float b) {
    return bf1(a) | (bf1(b) << 16);
}

// Pose one atom -> (X, Y) in physical coords.
__device__ inline float2 pose_one(const float* __restrict__ crd,
                                  const float* __restrict__ rot,
                                  const float* __restrict__ rot_init,
                                  const float* __restrict__ trans, int idx) {
    int b = idx >> 13;
    const float* p = crd + (long)idx * 3;
    float x0 = p[0], y0 = p[1], z0 = p[2];
    float q0 = x0 * rot_init[0] + y0 * rot_init[3] + z0 * rot_init[6] + trans[0];
    float q1 = x0 * rot_init[1] + y0 * rot_init[4] + z0 * rot_init[7] + trans[1];
    float q2 = x0 * rot_init[2] + y0 * rot_init[5] + z0 * rot_init[8] + trans[2];
    const float* R = rot + b * 9;
    float2 o;
    o.x = q0 * R[0] + q1 * R[1] + q2 * R[2];
    o.y = q0 * R[3] + q1 * R[4] + q2 * R[5];
    return o;
}

// ---------------------------------------------------------------------------
// R12 bucketing: HOME-TILE lists, no replication (R11's replicated scatter
// was the regression: 2.64x device-scope atomics + random writes -> 68us).
// Each in-window atom is stored ONCE in its home tile (column-major order
// tt = hx*24 + hy, so a column of tiles is one contiguous run). The splat
// covers its +-5 window by reading the 3 contiguous column segments of home
// columns tx-1..tx+1, rows ty-1..ty+1 -- the exact x/y masks (already in the
// chunk body) discard non-window atoms, chunk-tail overreads (further rows:
// y-masked; next column: x-dist >= 17; image end: 0x45 sentinel pad).
// ---------------------------------------------------------------------------
__global__ void count_atoms(const float* __restrict__ crd,
                            const float* __restrict__ rot,
                            const float* __restrict__ rot_init,
                            const float* __restrict__ trans,
                            int* __restrict__ counts,
                            float2* __restrict__ posed) {
    int idx = blockIdx.x * 256 + threadIdx.x;
    float2 v = pose_one(crd, rot, rot_init, trans, idx);
    posed[idx] = v;
    int icx = (int)rintf(v.x + 192.0f);
    int icy = (int)rintf(v.y + 192.0f);
    if (icx < -5 || icx > 388 || icy < -5 || icy > 388) return;
    int hx = min(max(icx, 0), DD - 1) >> 4;
    int hy = min(max(icy, 0), DD - 1) >> 4;
    atomicAdd(&counts[(idx >> 13) * NTILE + hx * NTX + hy], 1);
}

// Per-image exclusive scan of 576 exact tile counts (single pass, no pad).
__global__ __launch_bounds__(1024) void tile_scan(int* __restrict__ counts,
                                                  int* __restrict__ offs) {
    int b = blockIdx.x, t = threadIdx.x;
    int lane = t & 63, wid = t >> 6;     // 16 waves
    int* cnt = counts + b * NTILE;
    int* off = offs + b * OFFST;
    __shared__ int wsum[16];
    int v = (t < NTILE) ? cnt[t] : 0;
    int incl = v;
#pragma unroll
    for (int d = 1; d < 64; d <<= 1) {
        int u = __shfl_up(incl, d);
        if (lane >= d) incl += u;
    }
    if (lane == 63) wsum[wid] = incl;
    __syncthreads();
    if (wid == 0) {
        int s = (lane < 16) ? wsum[lane] : 0;
        int si = s;
#pragma unroll
        for (int d = 1; d < 16; d <<= 1) {
            int u = __shfl_up(si, d);
            if (lane >= d) si += u;
        }
        if (lane < 16) wsum[lane] = si - s;  // exclusive
    }
    __syncthreads();
    if (t < NTILE) {
        int excl = incl - v + wsum[wid];
        off[t] = excl;
        cnt[t] = 0;                      // reuse as scatter cursor
        if (t == NTILE - 1) off[NTILE] = excl + v;  // total in-window atoms
    }
}

__global__ void scatter_atoms(const float2* __restrict__ posed,
                              int* __restrict__ cursors,
                              const int* __restrict__ offs,
                              float2* __restrict__ lists) {
    int idx = blockIdx.x * 256 + threadIdx.x;
    float2 v = posed[idx];               // coalesced 8B re-read (same bits)
    int icx = (int)rintf(v.x + 192.0f);
    int icy = (int)rintf(v.y + 192.0f);
    if (icx < -5 || icx > 388 || icy < -5 || icy > 388) return;
    int b = idx >> 13;
    int hx = min(max(icx, 0), DD - 1) >> 4;
    int hy = min(max(icy, 0), DD - 1) >> 4;
    int tt = hx * NTX + hy;
    int pos = offs[b * OFFST + tt] + atomicAdd(&cursors[b * NTILE + tt], 1);
    lists[(long)b * LSTRIDE + pos] = v;
}

// ---------------------------------------------------------------------------
// MFMA splat, home-tile-direct (see R6/R12 notes). Gaussian separability:
// per 16x16 tile IMG = sum_a ey_a (x) ex_a = E_y^T*E_x, a GEMM with K =
// atoms; 32 atoms per mfma_f32_16x16x32_bf16. Per tile: 3 contiguous column
// segments (home cols tx-1..tx+1, rows ty-1..ty+1), chunked by 32 straight
// from global (16-lane broadcast f32x4 loads). Masks are exact => spurious /
// overread / sentinel atoms contribute exact 0. No LDS, no scan, no copying.
// Epilogue writes f32 Y and a bf16 (RNE) copy for stage-1's B operand.
// ---------------------------------------------------------------------------
__global__ __launch_bounds__(256) void splat_mfma(const float2* __restrict__ lists,
                                                  const int* __restrict__ offs,
                                                  float* __restrict__ img,
                                                  unsigned short* __restrict__ img_bf) {
    int b = blockIdx.z;
    int wv = __builtin_amdgcn_readfirstlane((int)(threadIdx.x >> 6));
    int lane = threadIdx.x & 63;
    int tx = blockIdx.x * 4 + wv;      // 0..23
    int ty = blockIdx.y;               // 0..23
    int c0 = tx * 16, r0 = ty * 16;

    const int* off = offs + b * OFFST;
    const float2* lb = lists + (long)b * LSTRIDE;

    f32x4 acc = {0.f, 0.f, 0.f, 0.f};
    int m = lane & 15;
    float rowf = (float)(r0 + m);        // a-side: pixel row (0..383)
    float colf = (float)(c0 + m);        // b-side: pixel col
    float py = rowf - 192.0f, px = colf - 192.0f;
    int g8 = (lane >> 4) << 3;           // k-slice base within chunk
    const float kneg = -0.32059868f;     // -(1/4.5)*log2(e)

    int rlo = max(ty - 1, 0), rhi = min(ty + 1, NTX - 1);
    int clo = max(tx - 1, 0), chi = min(tx + 1, NTX - 1);
    for (int c = clo; c <= chi; ++c) {
        int s = off[c * NTX + rlo];
        int e = off[c * NTX + rhi + 1];  // next tile's start (off[576]=total)
        for (int i = s; i < e; i += 32) {
            const f32x4* qp = (const f32x4*)(lb + i + g8);  // 2 atoms/read
            u32x4 au, bu;
#pragma unroll
            for (int p = 0; p < 4; p++) {
                f32x4 q = qp[p];         // (X0,Y0,X1,Y1); 16-lane broadcast
                // ey (row side)
                float d0 = py - q[1], d1 = py - q[3];
                float cy0 = rintf(q[1] + 192.0f), cy1 = rintf(q[3] + 192.0f);
                float e0 = (fabsf(rowf - cy0) <= 5.0f) ? exp2f(d0 * d0 * kneg) : 0.0f;
                float e1 = (fabsf(rowf - cy1) <= 5.0f) ? exp2f(d1 * d1 * kneg) : 0.0f;
                au[p] = bfpack(e0, e1);
                // ex (col side)
                float f0 = px - q[0], f1 = px - q[2];
                float cx0 = rintf(q[0] + 192.0f), cx1 = rintf(q[2] + 192.0f);
                float g0 = (fabsf(colf - cx0) <= 5.0f) ? exp2f(f0 * f0 * kneg) : 0.0f;
                float g1 = (fabsf(colf - cx1) <= 5.0f) ? exp2f(f1 * f1 * kneg) : 0.0f;
                bu[p] = bfpack(g0, g1);
            }
            short8 af = __builtin_bit_cast(short8, au);
            short8 bf = __builtin_bit_cast(short8, bu);
            acc = __builtin_amdgcn_mfma_f32_16x16x32_bf16(af, bf, acc, 0, 0, 0);
        }
    }

    // C layout: col = lane&15, row = (lane>>4)*4 + r  (same as gemm_mfma)
    int col = c0 + m;
    int rbase = r0 + (lane >> 4) * 4;
#pragma unroll
    for (int r = 0; r < 4; r++) {
        long o = ((long)b * DD + rbase + r) * DD + col;
        img[o] = acc[r];
        img_bf[o] = (unsigned short)bf1(acc[r]);
    }
}

// ---------------------------------------------------------------------------
// DFT-derived weights (bf16): Bt1 = [U; S] (768x384), Bt2 = [U|-2S] (384x768).
// y = U*Y*U - 2*S*Y*S == Re(f)-Im(f) of double-fftshifted FFT2.
// ---------------------------------------------------------------------------
__global__ void gen_w(unsigned short* __restrict__ Bt1,
                      unsigned short* __restrict__ Bt2) {
    int idx = blockIdx.x * 256 + threadIdx.x;
    if (idx >= DD * DD) return;
    int i = idx / DD, j = idx % DD;
    int t = (i - 192) * (j - 192);
    int r = t % DD;
    if (r < 0) r += DD;
    float th = (float)r * (6.28318530717958647692f / (float)DD);
    float s = sinf(th), c = cosf(th);
    Bt1[i * DD + j] = (unsigned short)bf1(c + s);
    Bt1[(DD + i) * DD + j] = (unsigned short)bf1(s);
    Bt2[i * 768 + j] = (unsigned short)bf1(c + s);
    Bt2[i * 768 + 384 + j] = (unsigned short)bf1(-2.0f * s);
}

// ---------------------------------------------------------------------------
// bf16 MFMA GEMM: C[row][col] = sum_k A[row][k] * B[col][k].
// A is the SHARED bf16 weight matrix (row stride K). B is BATCHED (stride sB).
// 1D grid + bijective XCD swizzle (R7: FETCH 117->27MB) + T2 LDS XOR swizzle
// (R9: bank-conflict 1.24e7 -> fixed, -40us). BFOLD: B is the folded view of
// stage-1's C' (768x384 bf16): B[i][k] = k<384 ? C'[i][k] : C'[384+i][k-384].
// ---------------------------------------------------------------------------
template <bool CBF16, bool BFOLD>
__global__ __launch_bounds__(256) void gemm_mfma(const unsigned short* __restrict__ Ag,
                                                 const unsigned short* __restrict__ Bg,
                                                 long sB,
                                                 void* __restrict__ Cg, long sC,
                                                 int K, int ldc, int nx, int bpi) {
    __shared__ uint4 lds4[2048];  // A: [0,1024), B: [1024,2048)

    int cpx = gridDim.x >> 3;                 // blocks per XCD chunk
    int wg = blockIdx.x;
    int lin = (wg & 7) * cpx + (wg >> 3);     // bijective XCD swizzle
    int bz = lin / bpi;
    int rr = lin - bz * bpi;
    int m0 = (rr / nx) * 128, n0 = (rr % nx) * 128;
    int tid = threadIdx.x;
    int lane = tid & 63, w = tid >> 6;
    int wm = w >> 1, wn = w & 1;

    f32x4 acc[4][4];
#pragma unroll
    for (int i = 0; i < 4; i++)
#pragma unroll
        for (int j = 0; j < 4; j++) acc[i][j] = (f32x4){0.f, 0.f, 0.f, 0.f};

    const unsigned short* Bh = Bg + (long)bz * sB;

    // read-side swizzled lane offset (same function of the logical index)
    int lsw = lane ^ (((lane >> 4) & 3) << 1);

    for (int k0 = 0; k0 < K; k0 += 64) {
        __syncthreads();
#pragma unroll
        for (int cc = 0; cc < 4; cc++) {
            int c = tid + cc * 256;
            int m = c >> 3, kc = (c & 7) << 3;
            int li = ((m >> 4) * 2 + (kc >> 5)) * 64 +
                     ((m & 15) | (((kc >> 3) & 3) << 4));
            li ^= ((kc >> 3) & 3) << 1;   // T2 swizzle (== ((li>>4)&3)<<1)
            // A tile (shared weights, always bf16, row stride K)
            lds4[li] = *(const uint4*)(Ag + (long)(m0 + m) * K + k0 + kc);
            // B tile (batched bf16)
            uint4 wv;
            if (BFOLD) {
                int kk = k0 + kc;  // 16B run stays within one 384-half (64|384)
                long boff = (kk >= 384)
                                ? ((long)(384 + n0 + m) * 384 + (kk - 384))
                                : ((long)(n0 + m) * 384 + kk);
                wv = *(const uint4*)(Bh + boff);
            } else {
                wv = *(const uint4*)(Bh + (long)(n0 + m) * K + k0 + kc);
            }
            lds4[1024 + li] = wv;
        }
        __syncthreads();
#pragma unroll
        for (int ki = 0; ki < 2; ki++) {
            short8 a[4], bfr[4];
#pragma unroll
            for (int i = 0; i < 4; i++)
                a[i] = *(const short8*)&lds4[((wm * 4 + i) * 2 + ki) * 64 + lsw];
#pragma unroll
            for (int j = 0; j < 4; j++)
                bfr[j] = *(const short8*)&lds4[1024 + ((wn * 4 + j) * 2 + ki) * 64 + lsw];
#pragma unroll
            for (int i = 0; i < 4; i++)
#pragma unroll
                for (int j = 0; j < 4; j++)
                    acc[i][j] = __builtin_amdgcn_mfma_f32_16x16x32_bf16(
                        a[i], bfr[j], acc[i][j], 0, 0, 0);
        }
    }

    int quad = lane >> 4, col0 = lane & 15;
#pragma unroll
    for (int i = 0; i < 4; i++)
#pragma unroll
        for (int j = 0; j < 4; j++)
#pragma unroll
            for (int r = 0; r < 4; r++) {
                int row = m0 + (wm * 4 + i) * 16 + quad * 4 + r;
                int cc2 = n0 + (wn * 4 + j) * 16 + col0;
                if (CBF16)
                    ((unsigned short*)Cg + (long)bz * sC)[(long)row * ldc + cc2] =
                        (unsigned short)bf1(acc[i][j][r]);
                else
                    ((float*)Cg + (long)bz * sC)[(long)row * ldc + cc2] = acc[i][j][r];
            }
}

extern "C" void kernel_launch(void* const* d_in, const int* in_sizes, int n_in,
                              void* d_out, int out_size, void* d_ws, size_t ws_size,
                              hipStream_t stream) {
    const float* crd      = (const float*)d_in[0];
    const float* rot      = (const float*)d_in[1];
    const float* rot_init = (const float*)d_in[2];
    const float* trans    = (const float*)d_in[3];

    float* out   = (float*)d_out;
    float* y     = out;                          // [64,384,384] hartley (fp32)
    float* yreal = out + (size_t)NB * DD * DD;   // [64,384,384] real image
    // Ybf16 staging lives in the y output region (18.9MB < 37.7MB): written
    // by splat, read by stage-1, overwritten by stage-2's final y write.
    unsigned short* Ybf = (unsigned short*)y;

    char* ws = (char*)d_ws;
    unsigned short* Bt1 = (unsigned short*)ws;              // [U;S]   768x384
    unsigned short* Bt2 = (unsigned short*)(ws + 589824);   // [U|-2S] 384x768
    char* Zb = ws + 1179648;                                // Z region (37.7MB)
    unsigned short* Z = (unsigned short*)Zb;                // 64x768x384 bf16 (Z^T)
    // Bucketing scratch aliases Z (all dead before stage-1 GEMM writes Z):
    int*    counts = (int*)Zb;                              // 64*576*4  = 147,456 B
    int*    offs   = (int*)(Zb + 147456);                   // 64*577*4  = 147,712 B
    float2* posed  = (float2*)(Zb + 295168);                // 4,194,304 B
    float2* lists  = (float2*)(Zb + 4489472);               // 64*8224*8 = 4,210,688 B
    // ends at 8,700,160 < 37,748,736 (Z size)

    hipMemsetAsync(counts, 0, (size_t)NB * NTILE * 4, stream);
    // Sentinel-fill the lists: 0x45454545 as float ~= 3.2e3 -> far outside
    // any tile => every mask false => pad/hole atoms contribute exact 0.
    hipMemsetAsync(lists, 0x45, (size_t)NB * LSTRIDE * 8, stream);

    count_atoms<<<(NB * NATOM) / 256, 256, 0, stream>>>(crd, rot, rot_init, trans,
                                                        counts, posed);
    tile_scan<<<NB, 1024, 0, stream>>>(counts, offs);
    scatter_atoms<<<(NB * NATOM) / 256, 256, 0, stream>>>(posed, counts, offs, lists);
    splat_mfma<<<dim3(6, 24, NB), 256, 0, stream>>>(lists, offs, yreal, Ybf);

    gen_w<<<(DD * DD + 255) / 256, 256, 0, stream>>>(Bt1, Bt2);

    // Stage 1 (swapped): C'[v][k] = sum_m Bt1[v][m]*Y[k][m] = Z^T,
    // M=768, N=384, K=384; A=Bt1 shared, B=Ybf batched bf16, C bf16.
    // nx=3 (384/128), bpi=3*6=18, nwg=18*64=1152 (div by 8 -> swizzle ok).
    gemm_mfma<true, false><<<1152, 256, 0, stream>>>(
        Bt1, Ybf, (long)DD * DD, (void*)Z, (long)768 * DD, DD, DD, 3, 18);

    // Stage 2 (swapped, folded-B): y[j][i] = sum_k Bt2[j][k]*Zt[i][k],
    // M=N=384, K=768; A=Bt2 shared, B=C' via fold addressing, C=y f32 direct.
    // nx=3, bpi=3*3=9, nwg=9*64=576 (div by 8 -> swizzle ok).
    gemm_mfma<false, true><<<576, 256, 0, stream>>>(
        Bt2, Z, (long)768 * DD, (void*)y, (long)DD * DD, 768, DD, 3, 9);
}

// Round 13
// 254.403 us; speedup vs baseline: 1.2576x; 1.2104x over previous
//
#include <hip/hip_runtime.h>

#define DD 384
#define NB 64
#define NATOM 8192
#define RB 394              // row buckets: icy+5, icy in [-5,388]
#define CB 51               // col buckets: (icx+16)>>3, icx in [-5,388] -> [1,50]
#define NBKT (RB * CB)      // 20094
#define OFFSTRIDE (NBKT + 4)
#define NCH 4               // scan chunks per image
#define CHSZ 5120           // buckets per chunk (4*5120 = 20480 >= NBKT)

typedef short short8 __attribute__((ext_vector_type(8)));
typedef float f32x4 __attribute__((ext_vector_type(4)));
typedef unsigned u32x4 __attribute__((ext_vector_type(4)));

// float -> bf16 (RNE) as ushort
__device__ inline unsigned bf1(float a) {
    unsigned u = __float_as_uint(a);
    return (u + 0x7FFFu + ((u >> 16) & 1u)) >> 16;
}
__device__ inline unsigned bfpack(float a, float b) {
    return bf1(a) | (bf1(b) << 16);
}

// Pose one atom -> (X, Y) in physical coords.
__device__ inline float2 pose_one(const float* __restrict__ crd,
                                  const float* __restrict__ rot,
                                  const float* __restrict__ rot_init,
                                  const float* __restrict__ trans, int idx) {
    int b = idx >> 13;
    const float* p = crd + (long)idx * 3;
    float x0 = p[0], y0 = p[1], z0 = p[2];
    float q0 = x0 * rot_init[0] + y0 * rot_init[3] + z0 * rot_init[6] + trans[0];
    float q1 = x0 * rot_init[1] + y0 * rot_init[4] + z0 * rot_init[7] + trans[1];
    float q2 = x0 * rot_init[2] + y0 * rot_init[5] + z0 * rot_init[8] + trans[2];
    const float* R = rot + b * 9;
    float2 o;
    o.x = q0 * R[0] + q1 * R[1] + q2 * R[2];
    o.y = q0 * R[3] + q1 * R[4] + q2 * R[5];
    return o;
}

// ---------------------------------------------------------------------------
// Bucketing (R10 structure): count (+ pose cache) -> scan -> scatter.
// R13: the scan is split into two fully-parallel kernels (R10's single-kernel
// version was 64 blocks x 20 SERIAL tiles, latency-bound, ~26us).
// ---------------------------------------------------------------------------
__global__ void count_atoms(const float* __restrict__ crd,
                            const float* __restrict__ rot,
                            const float* __restrict__ rot_init,
                            const float* __restrict__ trans,
                            int* __restrict__ counts,
                            float2* __restrict__ posed) {
    int idx = blockIdx.x * 256 + threadIdx.x;
    float2 v = pose_one(crd, rot, rot_init, trans, idx);
    posed[idx] = v;
    int icx = (int)rintf(v.x + 192.0f);
    int icy = (int)rintf(v.y + 192.0f);
    if (icx < -5 || icx > 388 || icy < -5 || icy > 388) return;
    int bi = (icy + 5) * CB + ((icx + 16) >> 3);
    atomicAdd(&counts[(idx >> 13) * NBKT + bi], 1);
}

// scan_a: one block per (image, chunk); local exclusive scan of 5120 buckets
// (5 coalesced 1024-tiles), zeroes cnt (scatter cursors), emits chunk total.
__global__ __launch_bounds__(1024) void scan_a(int* __restrict__ counts,
                                               int* __restrict__ offs,
                                               int* __restrict__ chunktot) {
    int bc = blockIdx.x;                 // image*NCH + chunk
    int b = bc >> 2, ch = bc & 3;
    int base = ch * CHSZ;
    int t = threadIdx.x, lane = t & 63, wid = t >> 6;
    int* cnt = counts + b * NBKT;
    int* off = offs + b * OFFSTRIDE;
    __shared__ int wsum[16];
    __shared__ int carrySm;
    if (t == 0) carrySm = 0;
    __syncthreads();
    for (int tile = 0; tile < 5; ++tile) {
        int k = base + tile * 1024 + t;
        int v = (k < NBKT) ? cnt[k] : 0;  // coalesced
        int incl = v;
#pragma unroll
        for (int d = 1; d < 64; d <<= 1) {
            int u = __shfl_up(incl, d);
            if (lane >= d) incl += u;
        }
        if (lane == 63) wsum[wid] = incl;
        __syncthreads();
        if (wid == 0) {
            int s = (lane < 16) ? wsum[lane] : 0;
            int si = s;
#pragma unroll
            for (int d = 1; d < 16; d <<= 1) {
                int u = __shfl_up(si, d);
                if (lane >= d) si += u;
            }
            if (lane < 16) wsum[lane] = si - s;  // exclusive
        }
        __syncthreads();
        int excl = incl - v + wsum[wid] + carrySm;
        if (k < NBKT) {
            off[k] = excl;               // chunk-local exclusive scan
            cnt[k] = 0;                  // reuse as scatter cursor
        }
        __syncthreads();                 // reads of carrySm done before bump
        if (t == 1023) carrySm = excl + v;  // = carry_in + tile total
        __syncthreads();
    }
    if (t == 0) chunktot[bc] = carrySm;  // chunk total
}

// scan_b: one block per (image, chunk); adds the sum of preceding chunks'
// totals to this chunk's entries. Chunk-0 blocks write off[NBKT] = total.
__global__ __launch_bounds__(1024) void scan_b(int* __restrict__ offs,
                                               const int* __restrict__ chunktot) {
    int bc = blockIdx.x;
    int b = bc >> 2, ch = bc & 3;
    const int* ct = chunktot + b * NCH;
    int* off = offs + b * OFFSTRIDE;
    int t = threadIdx.x;
    if (ch == 0) {
        if (t == 0) off[NBKT] = ct[0] + ct[1] + ct[2] + ct[3];
        return;
    }
    int basev = 0;
    for (int i = 0; i < ch; i++) basev += ct[i];
    int k0 = ch * CHSZ;
    for (int tile = 0; tile < 5; ++tile) {
        int k = k0 + tile * 1024 + t;
        if (k < NBKT) off[k] += basev;   // coalesced RMW
    }
}

__global__ void scatter_atoms(const float2* __restrict__ posed,
                              int* __restrict__ cursors,
                              const int* __restrict__ offs,
                              float2* __restrict__ sorted) {
    int idx = blockIdx.x * 256 + threadIdx.x;
    float2 v = posed[idx];               // coalesced 8B re-read (same bits)
    int icx = (int)rintf(v.x + 192.0f);
    int icy = (int)rintf(v.y + 192.0f);
    if (icx < -5 || icx > 388 || icy < -5 || icy > 388) return;
    int b = idx >> 13;
    int bi = (icy + 5) * CB + ((icx + 16) >> 3);
    int pos = offs[b * OFFSTRIDE + bi] + atomicAdd(&cursors[b * NBKT + bi], 1);
    sorted[(long)b * NATOM + pos] = v;
}

// ---------------------------------------------------------------------------
// MFMA splat (R10 structure, verified best: never entered the >=55us top-5).
// Gaussian separability: per 16x16 tile IMG = sum_a ey_a (x) ex_a = E_y^T*E_x
// -- a GEMM with K = atoms; 32 atoms per mfma_f32_16x16x32_bf16. Lanes 0..25
// gather the tile's exact-window atoms (fine row buckets, 1.23x x-overread)
// into a wave-private LDS list via shfl prefix-scan; MFMA phase computes
// ey/ex with exact |d|<=5 masks and bf16 RNE pack. R12's "simpler" home-tile
// direct-read variant was 3.4x atom-amplified and 70% slower -- the
// compaction here pays ~15us of orchestration to avoid ~50us of masked VALU.
// Epilogue writes f32 Y and a bf16 (RNE) copy for stage-1's B operand.
// ---------------------------------------------------------------------------
#define LCAP 512
#define LSZ  544   // LCAP + 32 pad slots

__global__ __launch_bounds__(256) void splat_mfma(const float2* __restrict__ sorted,
                                                  const int* __restrict__ offs,
                                                  float* __restrict__ img,
                                                  unsigned short* __restrict__ img_bf) {
    __shared__ __align__(16) float2 list[4][LSZ];
    int b = blockIdx.z;
    int wv = __builtin_amdgcn_readfirstlane((int)(threadIdx.x >> 6));
    int lane = threadIdx.x & 63;
    int tx = blockIdx.x * 4 + wv;      // 0..23
    int ty = blockIdx.y;               // 0..23
    int c0 = tx * 16, r0 = ty * 16;

    const int* off = offs + b * OFFSTRIDE;
    const float2* srt = sorted + (long)b * NATOM;

    int cb_lo = (c0 + 11) >> 3;          // loaded x-window [c0-8, c0+23]
    int cb_end = ((c0 + 36) >> 3) + 1;

    int cur = 0, iend = 0;
    if (lane < 26) {                     // one lane per row-bucket
        int rb = r0 + lane;              // icy = rb-5 in [r0-5, r0+20]
        cur = off[rb * CB + cb_lo];
        iend = off[rb * CB + cb_end];
    }

    f32x4 acc = {0.f, 0.f, 0.f, 0.f};
    int m = lane & 15;
    float rowf = (float)(r0 + m);        // a-side: pixel row (0..383)
    float colf = (float)(c0 + m);        // b-side: pixel col
    float py = rowf - 192.0f, px = colf - 192.0f;
    int g8 = (lane >> 4) << 3;           // k-slice base within chunk
    const float kneg = -0.32059868f;     // -(1/4.5)*log2(e)
    float2* wl = list[wv];

    for (int round = 0; round < 24; ++round) {
        int len = (lane < 26) ? (iend - cur) : 0;
        int incl = len;                  // exclusive scan via shfl_up
#pragma unroll
        for (int d = 1; d < 64; d <<= 1) {
            int t = __shfl_up(incl, d);
            if (lane >= d) incl += t;
        }
        int excl = incl - len;
        int totrem = __builtin_amdgcn_readfirstlane(__shfl(incl, 63));
        if (totrem == 0) break;
        int total = min(totrem, LCAP);
        int cnt = min(len, max(0, LCAP - excl));
        for (int j = 0; j < cnt; j++) wl[excl + j] = srt[cur + j];
        cur += cnt;
        int padn = (32 - (total & 31)) & 31;
        if (lane < padn) wl[total + lane] = (float2){3.0e5f, 3.0e5f};
        asm volatile("s_waitcnt lgkmcnt(0)" ::: "memory");  // wave-local LDS fence
        __builtin_amdgcn_sched_barrier(0);                  // no hoist past fence

        int nch = (total + 31) >> 5;
        for (int ch = 0; ch < nch; ch++) {
            const f32x4* qp = (const f32x4*)&wl[ch * 32 + g8];  // 2 atoms per read
            u32x4 au, bu;
#pragma unroll
            for (int p = 0; p < 4; p++) {
                f32x4 q = qp[p];         // (X0,Y0,X1,Y1); 16-lane broadcast
                // ey (row side)
                float d0 = py - q[1], d1 = py - q[3];
                float cy0 = rintf(q[1] + 192.0f), cy1 = rintf(q[3] + 192.0f);
                float e0 = (fabsf(rowf - cy0) <= 5.0f) ? exp2f(d0 * d0 * kneg) : 0.0f;
                float e1 = (fabsf(rowf - cy1) <= 5.0f) ? exp2f(d1 * d1 * kneg) : 0.0f;
                au[p] = bfpack(e0, e1);
                // ex (col side)
                float f0 = px - q[0], f1 = px - q[2];
                float cx0 = rintf(q[0] + 192.0f), cx1 = rintf(q[2] + 192.0f);
                float g0 = (fabsf(colf - cx0) <= 5.0f) ? exp2f(f0 * f0 * kneg) : 0.0f;
                float g1 = (fabsf(colf - cx1) <= 5.0f) ? exp2f(f1 * f1 * kneg) : 0.0f;
                bu[p] = bfpack(g0, g1);
            }
            short8 af = __builtin_bit_cast(short8, au);
            short8 bf = __builtin_bit_cast(short8, bu);
            acc = __builtin_amdgcn_mfma_f32_16x16x32_bf16(af, bf, acc, 0, 0, 0);
        }
        if (totrem <= LCAP) break;       // everything consumed this round
    }

    // C layout: col = lane&15, row = (lane>>4)*4 + r  (same as gemm_mfma)
    int col = c0 + m;
    int rbase = r0 + (lane >> 4) * 4;
#pragma unroll
    for (int r = 0; r < 4; r++) {
        long o = ((long)b * DD + rbase + r) * DD + col;
        img[o] = acc[r];
        img_bf[o] = (unsigned short)bf1(acc[r]);
    }
}

// ---------------------------------------------------------------------------
// DFT-derived weights (bf16): Bt1 = [U; S] (768x384), Bt2 = [U|-2S] (384x768).
// y = U*Y*U - 2*S*Y*S == Re(f)-Im(f) of double-fftshifted FFT2.
// ---------------------------------------------------------------------------
__global__ void gen_w(unsigned short* __restrict__ Bt1,
                      unsigned short* __restrict__ Bt2) {
    int idx = blockIdx.x * 256 + threadIdx.x;
    if (idx >= DD * DD) return;
    int i = idx / DD, j = idx % DD;
    int t = (i - 192) * (j - 192);
    int r = t % DD;
    if (r < 0) r += DD;
    float th = (float)r * (6.28318530717958647692f / (float)DD);
    float s = sinf(th), c = cosf(th);
    Bt1[i * DD + j] = (unsigned short)bf1(c + s);
    Bt1[(DD + i) * DD + j] = (unsigned short)bf1(s);
    Bt2[i * 768 + j] = (unsigned short)bf1(c + s);
    Bt2[i * 768 + 384 + j] = (unsigned short)bf1(-2.0f * s);
}

// ---------------------------------------------------------------------------
// bf16 MFMA GEMM: C[row][col] = sum_k A[row][k] * B[col][k].
// A is the SHARED bf16 weight matrix (row stride K). B is BATCHED (stride sB).
// 1D grid + bijective XCD swizzle (R7: FETCH 117->27MB) + T2 LDS XOR swizzle
// (R9: bank-conflict 1.24e7 -> fixed, -40us). BFOLD: B is the folded view of
// stage-1's C' (768x384 bf16): B[i][k] = k<384 ? C'[i][k] : C'[384+i][k-384].
// ---------------------------------------------------------------------------
template <bool CBF16, bool BFOLD>
__global__ __launch_bounds__(256) void gemm_mfma(const unsigned short* __restrict__ Ag,
                                                 const unsigned short* __restrict__ Bg,
                                                 long sB,
                                                 void* __restrict__ Cg, long sC,
                                                 int K, int ldc, int nx, int bpi) {
    __shared__ uint4 lds4[2048];  // A: [0,1024), B: [1024,2048)

    int cpx = gridDim.x >> 3;                 // blocks per XCD chunk
    int wg = blockIdx.x;
    int lin = (wg & 7) * cpx + (wg >> 3);     // bijective XCD swizzle
    int bz = lin / bpi;
    int rr = lin - bz * bpi;
    int m0 = (rr / nx) * 128, n0 = (rr % nx) * 128;
    int tid = threadIdx.x;
    int lane = tid & 63, w = tid >> 6;
    int wm = w >> 1, wn = w & 1;

    f32x4 acc[4][4];
#pragma unroll
    for (int i = 0; i < 4; i++)
#pragma unroll
        for (int j = 0; j < 4; j++) acc[i][j] = (f32x4){0.f, 0.f, 0.f, 0.f};

    const unsigned short* Bh = Bg + (long)bz * sB;

    // read-side swizzled lane offset (same function of the logical index)
    int lsw = lane ^ (((lane >> 4) & 3) << 1);

    for (int k0 = 0; k0 < K; k0 += 64) {
        __syncthreads();
#pragma unroll
        for (int cc = 0; cc < 4; cc++) {
            int c = tid + cc * 256;
            int m = c >> 3, kc = (c & 7) << 3;
            int li = ((m >> 4) * 2 + (kc >> 5)) * 64 +
                     ((m & 15) | (((kc >> 3) & 3) << 4));
            li ^= ((kc >> 3) & 3) << 1;   // T2 swizzle (== ((li>>4)&3)<<1)
            // A tile (shared weights, always bf16, row stride K)
            lds4[li] = *(const uint4*)(Ag + (long)(m0 + m) * K + k0 + kc);
            // B tile (batched bf16)
            uint4 wv;
            if (BFOLD) {
                int kk = k0 + kc;  // 16B run stays within one 384-half (64|384)
                long boff = (kk >= 384)
                                ? ((long)(384 + n0 + m) * 384 + (kk - 384))
                                : ((long)(n0 + m) * 384 + kk);
                wv = *(const uint4*)(Bh + boff);
            } else {
                wv = *(const uint4*)(Bh + (long)(n0 + m) * K + k0 + kc);
            }
            lds4[1024 + li] = wv;
        }
        __syncthreads();
#pragma unroll
        for (int ki = 0; ki < 2; ki++) {
            short8 a[4], bfr[4];
#pragma unroll
            for (int i = 0; i < 4; i++)
                a[i] = *(const short8*)&lds4[((wm * 4 + i) * 2 + ki) * 64 + lsw];
#pragma unroll
            for (int j = 0; j < 4; j++)
                bfr[j] = *(const short8*)&lds4[1024 + ((wn * 4 + j) * 2 + ki) * 64 + lsw];
#pragma unroll
            for (int i = 0; i < 4; i++)
#pragma unroll
                for (int j = 0; j < 4; j++)
                    acc[i][j] = __builtin_amdgcn_mfma_f32_16x16x32_bf16(
                        a[i], bfr[j], acc[i][j], 0, 0, 0);
        }
    }

    int quad = lane >> 4, col0 = lane & 15;
#pragma unroll
    for (int i = 0; i < 4; i++)
#pragma unroll
        for (int j = 0; j < 4; j++)
#pragma unroll
            for (int r = 0; r < 4; r++) {
                int row = m0 + (wm * 4 + i) * 16 + quad * 4 + r;
                int cc2 = n0 + (wn * 4 + j) * 16 + col0;
                if (CBF16)
                    ((unsigned short*)Cg + (long)bz * sC)[(long)row * ldc + cc2] =
                        (unsigned short)bf1(acc[i][j][r]);
                else
                    ((float*)Cg + (long)bz * sC)[(long)row * ldc + cc2] = acc[i][j][r];
            }
}

extern "C" void kernel_launch(void* const* d_in, const int* in_sizes, int n_in,
                              void* d_out, int out_size, void* d_ws, size_t ws_size,
                              hipStream_t stream) {
    const float* crd      = (const float*)d_in[0];
    const float* rot      = (const float*)d_in[1];
    const float* rot_init = (const float*)d_in[2];
    const float* trans    = (const float*)d_in[3];

    float* out   = (float*)d_out;
    float* y     = out;                          // [64,384,384] hartley (fp32)
    float* yreal = out + (size_t)NB * DD * DD;   // [64,384,384] real image
    // Ybf16 staging lives in the y output region (18.9MB < 37.7MB): written
    // by splat, read by stage-1, overwritten by stage-2's final y write.
    unsigned short* Ybf = (unsigned short*)y;

    char* ws = (char*)d_ws;
    unsigned short* Bt1 = (unsigned short*)ws;              // [U;S]   768x384
    unsigned short* Bt2 = (unsigned short*)(ws + 589824);   // [U|-2S] 384x768
    char* Zb = ws + 1179648;                                // Z region (37.7MB)
    unsigned short* Z = (unsigned short*)Zb;                // 64x768x384 bf16 (Z^T)
    // Bucketing scratch aliases Z (all dead before stage-1 GEMM writes Z):
    int*    counts  = (int*)Zb;                             // 64*20094*4 = 5,144,064 B
    int*    offs    = (int*)(Zb + 5144064);                 // 64*20098*4 = 5,145,088 B
    float2* sorted  = (float2*)(Zb + 10289152);             // 4,194,304 B
    float2* posed   = (float2*)(Zb + 14483456);             // 4,194,304 B
    int*    chunktot= (int*)(Zb + 18677760);                // 256*4 = 1,024 B
    // ends at 18,678,784 < 37,748,736 (Z size)

    hipMemsetAsync(counts, 0, (size_t)NB * NBKT * 4, stream);

    count_atoms<<<(NB * NATOM) / 256, 256, 0, stream>>>(crd, rot, rot_init, trans,
                                                        counts, posed);
    scan_a<<<NB * NCH, 1024, 0, stream>>>(counts, offs, chunktot);
    scan_b<<<NB * NCH, 1024, 0, stream>>>(offs, chunktot);
    scatter_atoms<<<(NB * NATOM) / 256, 256, 0, stream>>>(posed, counts, offs, sorted);
    splat_mfma<<<dim3(6, 24, NB), 256, 0, stream>>>(sorted, offs, yreal, Ybf);

    gen_w<<<(DD * DD + 255) / 256, 256, 0, stream>>>(Bt1, Bt2);

    // Stage 1 (swapped): C'[v][k] = sum_m Bt1[v][m]*Y[k][m] = Z^T,
    // M=768, N=384, K=384; A=Bt1 shared, B=Ybf batched bf16, C bf16.
    // nx=3 (384/128), bpi=3*6=18, nwg=18*64=1152 (div by 8 -> swizzle ok).
    gemm_mfma<true, false><<<1152, 256, 0, stream>>>(
        Bt1, Ybf, (long)DD * DD, (void*)Z, (long)768 * DD, DD, DD, 3, 18);

    // Stage 2 (swapped, folded-B): y[j][i] = sum_k Bt2[j][k]*Zt[i][k],
    // M=N=384, K=768; A=Bt2 shared, B=C' via fold addressing, C=y f32 direct.
    // nx=3, bpi=3*3=9, nwg=9*64=576 (div by 8 -> swizzle ok).
    gemm_mfma<false, true><<<576, 256, 0, stream>>>(
        Bt2, Z, (long)768 * DD, (void*)y, (long)DD * DD, 768, DD, 3, 9);
}